// Round 2
// baseline (603.862 us; speedup 1.0000x reference)
//
#include <hip/hip_runtime.h>
#include <stdint.h>

#define Bn   2048
#define Nn   20
#define Dn   512
#define Hn   8
#define Mn   (Bn*Nn)      // 40960 rows
#define K3n  1536
#define NPn  22           // padded sequence rows
#define BKn  32

typedef __attribute__((ext_vector_type(4))) float  floatx4;
typedef __attribute__((ext_vector_type(8))) __bf16 bf16x8;
typedef __attribute__((ext_vector_type(4))) __bf16 bf16x4;

// -------- async global->LDS, 16B per lane; LDS base must be wave-uniform ----
__device__ __forceinline__ void gload_lds16(const void* g, void* l) {
  __builtin_amdgcn_global_load_lds(
      (const __attribute__((address_space(1))) void*)g,
      (__attribute__((address_space(3))) void*)l, 16, 0, 0);
}

// ============================ prep kernels ==================================
// Xpad[b][0]=0, Xpad[b][n]=bf16(x[b][n-1]), Xpad[b][21]=0
__global__ void k_prep_xpad(const float* __restrict__ x, __bf16* __restrict__ xpad) {
  int idx = blockIdx.x * 256 + threadIdx.x;      // over B*22*64 chunks of 8
  int d8 = idx & 63;
  int t  = idx >> 6;                              // b*22 + n
  if (t >= Bn * NPn) return;
  int n = t % NPn;
  int b = t / NPn;
  bf16x8 v;
  if (n == 0 || n == NPn - 1) {
#pragma unroll
    for (int e = 0; e < 8; ++e) v[e] = (__bf16)0.f;
  } else {
    const float4 x0 = *(const float4*)(x + (size_t)((b * Nn + n - 1) * Dn) + d8 * 8);
    const float4 x1 = *(const float4*)(x + (size_t)((b * Nn + n - 1) * Dn) + d8 * 8 + 4);
    v[0] = (__bf16)x0.x; v[1] = (__bf16)x0.y; v[2] = (__bf16)x0.z; v[3] = (__bf16)x0.w;
    v[4] = (__bf16)x1.x; v[5] = (__bf16)x1.y; v[6] = (__bf16)x1.z; v[7] = (__bf16)x1.w;
  }
  *(bf16x8*)(xpad + (size_t)t * Dn + d8 * 8) = v;
}

// WcT[j][kk]: j = seg*512+o (q|k|v), kk = kker*512+i ; = Wseg[o][i][kker]
__global__ void k_prep_wct(const float* __restrict__ Wq, const float* __restrict__ Wk,
                           const float* __restrict__ Wv, __bf16* __restrict__ wct) {
  int idx = blockIdx.x * 256 + threadIdx.x;
  if (idx >= K3n * K3n) return;
  int kk = idx % K3n;
  int j  = idx / K3n;
  int seg = j >> 9, o = j & 511;
  int kker = kk >> 9, i = kk & 511;
  const float* W = (seg == 0) ? Wq : ((seg == 1) ? Wk : Wv);
  wct[idx] = (__bf16)W[(o * 512 + i) * 3 + kker];
}

// WoT[c][k] = Wo[k][c]
__global__ void k_prep_wot(const float* __restrict__ Wo, __bf16* __restrict__ wot) {
  int idx = blockIdx.x * 256 + threadIdx.x;
  if (idx >= Dn * Dn) return;
  int k = idx & 511, c = idx >> 9;
  wot[idx] = (__bf16)Wo[k * Dn + c];
}

// WqfT[dq][d] = Wqf[d][dq]
__global__ void k_prep_wqft(const float* __restrict__ Wqf, __bf16* __restrict__ wqft) {
  int idx = blockIdx.x * 256 + threadIdx.x;
  if (idx >= Dn * 64) return;
  int d = idx & 511, dq = idx >> 9;
  wqft[idx] = (__bf16)Wqf[d * 64 + dq];
}

// bias[h][i][j] = rel_table[i-j+19][h] + alpha*gsb[h][i][j] + bqp[h]
__global__ void k_bias(const float* __restrict__ rel, const float* __restrict__ gsb,
                       const float* __restrict__ alpha, const float* __restrict__ bqp,
                       float* __restrict__ bias) {
  int idx = blockIdx.x * 256 + threadIdx.x;
  if (idx >= Hn * Nn * Nn) return;
  int j = idx % Nn;
  int i = (idx / Nn) % Nn;
  int h = idx / (Nn * Nn);
  bias[idx] = rel[(i - j + Nn - 1) * Hn + h] + alpha[0] * gsb[idx] + bqp[h];
}

// ===== shared pipelined-GEMM step machinery (128x512 tile, BK=32) ===========
// Used by k_qkv and k_oproj. Requires in-scope symbols:
//   lds, gA, gB0..gB3, dA, dB, fAo0..fAo3, fBo[8], acc[4][8]
// Per K-step: 2 phases x {ds_read subtile; stage share; s_barrier; setprio;
// 16 MFMA; setprio}; counted vmcnt(5) ONLY at step end (T3+T4), raw
// s_barrier throughout (never __syncthreads inside the loop).
#define PIPE_STAGE_A(NB) do {                                          \
    __bf16* _s = lds + (NB) * 20480;                                   \
    gload_lds16(gA,  _s + dA);          gA  += BKn;                    \
    gload_lds16(gB0, _s + dB);          gB0 += BKn;                    \
    gload_lds16(gB1, _s + dB + 512);    gB1 += BKn;                    \
  } while (0)
#define PIPE_STAGE_B(NB) do {                                          \
    __bf16* _s = lds + (NB) * 20480;                                   \
    gload_lds16(gB2, _s + dB + 1024);   gB2 += BKn;                    \
    gload_lds16(gB3, _s + dB + 1536);   gB3 += BKn;                    \
  } while (0)

#define PIPE_HALF(_L, NLO, STG) do {                                   \
    bf16x8 _b[4];                                                      \
    _b[0] = *(const bf16x8*)((_L) + fBo[(NLO) + 0]);                   \
    _b[1] = *(const bf16x8*)((_L) + fBo[(NLO) + 1]);                   \
    _b[2] = *(const bf16x8*)((_L) + fBo[(NLO) + 2]);                   \
    _b[3] = *(const bf16x8*)((_L) + fBo[(NLO) + 3]);                   \
    STG;                                                               \
    asm volatile("s_barrier" ::: "memory");                            \
    __builtin_amdgcn_s_setprio(1);                                     \
    _Pragma("unroll")                                                  \
    for (int _n = 0; _n < 4; ++_n) {                                   \
      acc[0][(NLO) + _n] = __builtin_amdgcn_mfma_f32_16x16x32_bf16(_a0, _b[_n], acc[0][(NLO) + _n], 0, 0, 0); \
      acc[1][(NLO) + _n] = __builtin_amdgcn_mfma_f32_16x16x32_bf16(_a1, _b[_n], acc[1][(NLO) + _n], 0, 0, 0); \
      acc[2][(NLO) + _n] = __builtin_amdgcn_mfma_f32_16x16x32_bf16(_a2, _b[_n], acc[2][(NLO) + _n], 0, 0, 0); \
      acc[3][(NLO) + _n] = __builtin_amdgcn_mfma_f32_16x16x32_bf16(_a3, _b[_n], acc[3][(NLO) + _n], 0, 0, 0); \
    }                                                                  \
    __builtin_amdgcn_s_setprio(0);                                     \
  } while (0)

#define PIPE_STEP(CB, NB, DOSTAGE, VMS) do {                           \
    const __bf16* _L = lds + (CB) * 20480;                             \
    bf16x8 _a0 = *(const bf16x8*)(_L + fAo0);                          \
    bf16x8 _a1 = *(const bf16x8*)(_L + fAo1);                          \
    bf16x8 _a2 = *(const bf16x8*)(_L + fAo2);                          \
    bf16x8 _a3 = *(const bf16x8*)(_L + fAo3);                          \
    PIPE_HALF(_L, 0, if (DOSTAGE) PIPE_STAGE_A(NB));                   \
    asm volatile("s_barrier" ::: "memory");                            \
    PIPE_HALF(_L, 4, if (DOSTAGE) PIPE_STAGE_B(NB));                   \
    asm volatile("s_waitcnt vmcnt(" VMS ")\n\ts_barrier" ::: "memory");\
  } while (0)

// ================= QKV conv-GEMM + LayerNorm + residual =====================
// 128x512 tile (full segment width keeps LN fused), 8 waves (2x4), wave tile
// 64x128 = 4x8 frags of 16x16x32 bf16 MFMA. Triple-buffered LDS (3x40 KB),
// 2-step prefetch, counted vmcnt(5) at step end only. Each step = 2 phases
// (T3 interleave) so co-resident waves overlap LDS reads with MFMA clusters.
// LDS chunk swizzle: slot = koct ^ ((row>>1)&3) (2-way, free), staged via
// pre-swizzled global source (gload_lds dest must stay linear).
__global__ __launch_bounds__(512, 2)
void k_qkv(const __bf16* __restrict__ xpad, const __bf16* __restrict__ wct,
           const float* __restrict__ gq_g, const float* __restrict__ gq_b,
           const float* __restrict__ gk_g, const float* __restrict__ gk_b,
           const float* __restrict__ gv_g, const float* __restrict__ gv_b,
           __bf16* __restrict__ qkv) {
  __shared__ __bf16 lds[3 * 20480];   // 3 x (A 128x32 + B 512x32) = 120 KB
  __shared__ float red1[512];
  __shared__ float red2[512];

  const int tid  = threadIdx.x;
  const int wave = tid >> 6;
  const int lane = tid & 63;
  const int quad = lane >> 4;
  const int l15  = lane & 15;
  const int rowg = wave >> 2;          // 0..1
  const int colg = wave & 3;           // 0..3

  // XCD-aware swizzle: 8 XCDs x 40 m-tiles x 3 segs (960 % 8 == 0, bijective)
  const int bid   = blockIdx.x;
  const int xcd   = bid & 7;
  const int local = bid >> 3;          // 0..119
  const int seg   = local % 3;
  const int mt    = xcd * 40 + local / 3;
  const int m0    = mt * 128;

  // --- staging source pointers (per-lane, pre-swizzled k-octet) ---
  const __bf16 *gB0, *gB1, *gB2, *gB3;
  {
    int c, col, rk;
    c = wave * 256 + 0 * 64 + lane; col = c >> 2; rk = (c & 3) ^ ((col >> 1) & 3);
    gB0 = wct + (size_t)(seg * 512 + col) * K3n + rk * 8;
    c = wave * 256 + 1 * 64 + lane; col = c >> 2; rk = (c & 3) ^ ((col >> 1) & 3);
    gB1 = wct + (size_t)(seg * 512 + col) * K3n + rk * 8;
    c = wave * 256 + 2 * 64 + lane; col = c >> 2; rk = (c & 3) ^ ((col >> 1) & 3);
    gB2 = wct + (size_t)(seg * 512 + col) * K3n + rk * 8;
    c = wave * 256 + 3 * 64 + lane; col = c >> 2; rk = (c & 3) ^ ((col >> 1) & 3);
    gB3 = wct + (size_t)(seg * 512 + col) * K3n + rk * 8;
  }
  const __bf16* gA;
  {
    int c   = tid;                     // A chunk id (0..511), 1 per thread
    int row = c >> 2;
    int rk  = (c & 3) ^ ((row >> 1) & 3);
    int grow = m0 + row;
    int b = grow / Nn, n = grow - b * Nn;
    gA = xpad + (size_t)(b * NPn + n) * Dn + rk * 8;  // covers x rows n-1..n+1
  }

  // --- fixed LDS fragment element-offsets (buffer-relative) ---
  int fAo0, fAo1, fAo2, fAo3, fBo[8];
  {
    int row;
    row = rowg * 64 + 0 * 16 + l15; fAo0 = row * BKn + (quad ^ ((row >> 1) & 3)) * 8;
    row = rowg * 64 + 1 * 16 + l15; fAo1 = row * BKn + (quad ^ ((row >> 1) & 3)) * 8;
    row = rowg * 64 + 2 * 16 + l15; fAo2 = row * BKn + (quad ^ ((row >> 1) & 3)) * 8;
    row = rowg * 64 + 3 * 16 + l15; fAo3 = row * BKn + (quad ^ ((row >> 1) & 3)) * 8;
#pragma unroll
    for (int tc = 0; tc < 8; ++tc) {
      int col = colg * 128 + tc * 16 + l15;
      fBo[tc] = 4096 + col * BKn + (quad ^ ((col >> 1) & 3)) * 8;
    }
  }

  // --- staging LDS dest offsets (wave-uniform base; HW adds lane*16B) ---
  const int dA = wave * 512;               // A region: elements 0..4095
  const int dB = 4096 + wave * 2048;       // B region: elements 4096..20479

  floatx4 acc[4][8];
  const floatx4 zero = {0.f, 0.f, 0.f, 0.f};
#pragma unroll
  for (int i = 0; i < 4; ++i)
#pragma unroll
    for (int j = 0; j < 8; ++j) acc[i][j] = zero;

  // prologue: stage steps 0 and 1; wait for step-0 data (oldest 5 of 10)
  PIPE_STAGE_A(0); PIPE_STAGE_B(0);
  PIPE_STAGE_A(1); PIPE_STAGE_B(1);
  asm volatile("s_waitcnt vmcnt(5)\n\ts_barrier" ::: "memory");

  // main loop: 48 K-steps; step t computes buf t%3, stages t+2 into (t+2)%3
#pragma unroll 1
  for (int it = 0; it < 15; ++it) {          // steps 0..44
    PIPE_STEP(0, 2, true, "5");
    PIPE_STEP(1, 0, true, "5");
    PIPE_STEP(2, 1, true, "5");
  }
  PIPE_STEP(0, 2, true, "5");                // step 45 (stages step 47)
  PIPE_STEP(1, 0, false, "0");               // step 46
  PIPE_STEP(2, 0, false, "0");               // step 47

  // --- fused LayerNorm + residual epilogue ---
  float s1[16], s2[16];
#pragma unroll
  for (int m = 0; m < 4; ++m)
#pragma unroll
    for (int r = 0; r < 4; ++r) {
      float a = 0.f, b2 = 0.f;
#pragma unroll
      for (int n = 0; n < 8; ++n) { float v = acc[m][n][r]; a += v; b2 += v * v; }
      s1[m * 4 + r] = a; s2[m * 4 + r] = b2;
    }
#pragma unroll
  for (int off = 1; off < 16; off <<= 1)
#pragma unroll
    for (int i = 0; i < 16; ++i) {
      s1[i] += __shfl_xor(s1[i], off, 64);
      s2[i] += __shfl_xor(s2[i], off, 64);
    }
  if (l15 == 0) {
#pragma unroll
    for (int i = 0; i < 16; ++i) {
      int m = i >> 2, r = i & 3;
      int row = rowg * 64 + m * 16 + quad * 4 + r;
      red1[row * 4 + colg] = s1[i];
      red2[row * 4 + colg] = s2[i];
    }
  }
  __syncthreads();

  const float* gg = (seg == 0) ? gq_g : ((seg == 1) ? gk_g : gv_g);
  const float* bb = (seg == 0) ? gq_b : ((seg == 1) ? gk_b : gv_b);
#pragma unroll
  for (int m = 0; m < 4; ++m)
#pragma unroll
    for (int r = 0; r < 4; ++r) {
      int row = rowg * 64 + m * 16 + quad * 4 + r;
      float su = red1[row * 4] + red1[row * 4 + 1] + red1[row * 4 + 2] + red1[row * 4 + 3];
      float sq = red2[row * 4] + red2[row * 4 + 1] + red2[row * 4 + 2] + red2[row * 4 + 3];
      float mn = su * (1.f / 512.f);
      float vv = sq * (1.f / 512.f) - mn * mn;
      float rstd = rsqrtf(vv + 1e-5f);
      int grow = m0 + row;
      int b = grow / Nn, n2 = grow - b * Nn;
      const __bf16* xr = xpad + (size_t)(b * NPn + n2 + 1) * Dn;  // bf16 residual (L2-hot)
#pragma unroll
      for (int n = 0; n < 8; ++n) {
        int col = colg * 128 + n * 16 + l15;
        float val = (acc[m][n][r] - mn) * rstd * gg[col] + bb[col] + (float)xr[col];
        qkv[(size_t)grow * K3n + seg * 512 + col] = (__bf16)val;
      }
    }
}

// ======== qfp = tanh(x @ Wqf + bqf) @ Wqp  (fused, fp32 out) ================
// Block: 64 rows x 64 cols, 256 thr = 4 waves, wave = 16 rows x 64 cols. K=512.
// Epilogue: per-row dot with Wqp via shfl reduction over l15 -> qfp[row][8].
__global__ __launch_bounds__(256)
void k_qfqp(const __bf16* __restrict__ xpad, const __bf16* __restrict__ wqft,
            const float* __restrict__ bqf, const float* __restrict__ wqp,
            float* __restrict__ qfp) {
  __shared__ __bf16 lA[64 * BKn];
  __shared__ __bf16 lB[64 * BKn];
  __shared__ float lWqpT[8 * 64];   // [h][col]
  const int tid  = threadIdx.x;
  const int wave = tid >> 6;
  const int lane = tid & 63;
  const int quad = lane >> 4;
  const int l15  = lane & 15;
  const int m0   = blockIdx.x * 64;

#pragma unroll
  for (int t = tid; t < 512; t += 256) {
    int col = t & 63, h = t >> 6;
    lWqpT[t] = wqp[col * 8 + h];
  }

  int c = wave * 64 + lane;
  int rowc = c >> 2;
  int rk   = (c & 3) ^ ((rowc >> 1) & 3);
  int grow = m0 + rowc;
  int b = grow / Nn, n = grow - b * Nn;
  const __bf16* gA = xpad + (size_t)(b * NPn + n + 1) * Dn + rk * 8;  // x[b][n]
  const __bf16* gB = wqft + (size_t)rowc * Dn + rk * 8;

  int frow = wave * 16 + l15;
  const __bf16* fA = lA + frow * BKn + (quad ^ ((frow >> 1) & 3)) * 8;
  const __bf16* fB[4];
#pragma unroll
  for (int tc = 0; tc < 4; ++tc) {
    int col = tc * 16 + l15;
    fB[tc] = lB + col * BKn + (quad ^ ((col >> 1) & 3)) * 8;
  }

  const floatx4 zero = {0.f, 0.f, 0.f, 0.f};
  floatx4 acc[4] = {zero, zero, zero, zero};

  for (int kt = 0; kt < Dn / BKn; ++kt) {
    gload_lds16(gA, lA + wave * 512);
    gload_lds16(gB, lB + wave * 512);
    __syncthreads();
    bf16x8 a = *(const bf16x8*)fA;
#pragma unroll
    for (int tc = 0; tc < 4; ++tc)
      acc[tc] = __builtin_amdgcn_mfma_f32_16x16x32_bf16(a, *(const bf16x8*)fB[tc], acc[tc], 0, 0, 0);
    __syncthreads();
    gA += BKn; gB += BKn;
  }

  // epilogue: t = tanh(acc + bqf); qfp[row][h] = sum_col t*WqpT[h][col]
  float part[4][8];
#pragma unroll
  for (int r = 0; r < 4; ++r)
#pragma unroll
    for (int h = 0; h < 8; ++h) part[r][h] = 0.f;
#pragma unroll
  for (int tc = 0; tc < 4; ++tc) {
    int col = tc * 16 + l15;
    float bq = bqf[col];
#pragma unroll
    for (int r = 0; r < 4; ++r) {
      float t = tanhf(acc[tc][r] + bq);
#pragma unroll
      for (int h = 0; h < 8; ++h) part[r][h] += t * lWqpT[h * 64 + col];
    }
  }
#pragma unroll
  for (int off = 1; off < 16; off <<= 1)
#pragma unroll
    for (int r = 0; r < 4; ++r)
#pragma unroll
      for (int h = 0; h < 8; ++h) part[r][h] += __shfl_xor(part[r][h], off, 64);
  if (l15 == 0) {
#pragma unroll
    for (int r = 0; r < 4; ++r) {
      int row = wave * 16 + quad * 4 + r;
#pragma unroll
      for (int h = 0; h < 8; ++h)
        qfp[(size_t)(m0 + row) * 8 + h] = part[r][h];
    }
  }
}

// =========================== attention (fp32) ===============================
// One wave per (b,h). scores = qk^T/8 + bias[h] + qfp_i - qfp_j; softmax; @v.
__global__ __launch_bounds__(256)
void k_attn(const __bf16* __restrict__ qkv, const float* __restrict__ qfp,
            const float* __restrict__ bias, __bf16* __restrict__ aout) {
  __shared__ float sq[4][Nn * 64];
  __shared__ float sk[4][Nn * 68];
  __shared__ float sv[4][Nn * 68];
  __shared__ float sp[4][Nn * Nn];
  __shared__ float sf[4][Nn];
  const int tid  = threadIdx.x;
  const int w    = tid >> 6;
  const int lane = tid & 63;
  const int p0 = blockIdx.x * 4 + w;
  const int b = p0 >> 3, h = p0 & 7;
  const __bf16* qb = qkv + (size_t)b * Nn * K3n + h * 64;

  // vectorized staging: 160 bf16x8 chunks per matrix
  for (int idx = lane; idx < 160; idx += 64) {
    int n = idx >> 3, c = (idx & 7) * 8;
    bf16x8 qv = *(const bf16x8*)(qb + (size_t)n * K3n + c);
    bf16x8 kv = *(const bf16x8*)(qb + (size_t)n * K3n + 512 + c);
    bf16x8 vv = *(const bf16x8*)(qb + (size_t)n * K3n + 1024 + c);
#pragma unroll
    for (int e = 0; e < 8; ++e) {
      sq[w][n * 64 + c + e] = (float)qv[e];
      sk[w][n * 68 + c + e] = (float)kv[e];
      sv[w][n * 68 + c + e] = (float)vv[e];
    }
  }
  if (lane < Nn) sf[w][lane] = qfp[(size_t)(b * Nn + lane) * 8 + h];
  __syncthreads();

  // scores: all 64 lanes over 400 (i,j) pairs
  const float* bh = bias + h * Nn * Nn;
  for (int p = lane; p < Nn * Nn; p += 64) {
    int i = p / Nn, j = p - i * Nn;
    const float4* q4 = (const float4*)&sq[w][i * 64];
    const float4* k4 = (const float4*)&sk[w][j * 68];
    float s = 0.f;
#pragma unroll
    for (int d4 = 0; d4 < 16; ++d4) {
      float4 qa = q4[d4], ka = k4[d4];
      s += qa.x * ka.x + qa.y * ka.y + qa.z * ka.z + qa.w * ka.w;
    }
    sp[w][p] = s * 0.125f + bh[p] + sf[w][i] - sf[w][j];
  }
  __syncthreads();
  if (lane < Nn) {
    int i = lane;
    float* row = &sp[w][i * Nn];
    float mx = row[0];
    for (int j = 1; j < Nn; ++j) mx = fmaxf(mx, row[j]);
    float sum = 0.f;
    for (int j = 0; j < Nn; ++j) { float e = __expf(row[j] - mx); row[j] = e; sum += e; }
    float inv = 1.f / sum;
    for (int j = 0; j < Nn; ++j) row[j] *= inv;
  }
  __syncthreads();
  for (int i = 0; i < Nn; ++i) {
    float a = 0.f;
#pragma unroll
    for (int j = 0; j < Nn; ++j) a += sp[w][i * Nn + j] * sv[w][j * 68 + lane];
    aout[(size_t)(b * Nn + i) * Dn + h * 64 + lane] = (__bf16)a;
  }
}

// ==================== out = attn_out @ Wo + bo (fp32 out) ===================
// Same pipelined 128x512 structure as k_qkv (triple buffer, 2-phase steps,
// counted vmcnt). K = 512 -> 16 steps. Grid 320 = 8 XCDs x 40 tiles.
__global__ __launch_bounds__(512, 2)
void k_oproj(const __bf16* __restrict__ aout, const __bf16* __restrict__ wot,
             const float* __restrict__ bo, float* __restrict__ out) {
  __shared__ __bf16 lds[3 * 20480];   // 120 KB
  const int tid  = threadIdx.x;
  const int wave = tid >> 6;
  const int lane = tid & 63;
  const int quad = lane >> 4;
  const int l15  = lane & 15;
  const int rowg = wave >> 2;
  const int colg = wave & 3;

  const int bid = blockIdx.x;
  const int m0  = ((bid & 7) * 40 + (bid >> 3)) * 128;

  const __bf16 *gB0, *gB1, *gB2, *gB3;
  {
    int c, col, rk;
    c = wave * 256 + 0 * 64 + lane; col = c >> 2; rk = (c & 3) ^ ((col >> 1) & 3);
    gB0 = wot + (size_t)col * Dn + rk * 8;
    c = wave * 256 + 1 * 64 + lane; col = c >> 2; rk = (c & 3) ^ ((col >> 1) & 3);
    gB1 = wot + (size_t)col * Dn + rk * 8;
    c = wave * 256 + 2 * 64 + lane; col = c >> 2; rk = (c & 3) ^ ((col >> 1) & 3);
    gB2 = wot + (size_t)col * Dn + rk * 8;
    c = wave * 256 + 3 * 64 + lane; col = c >> 2; rk = (c & 3) ^ ((col >> 1) & 3);
    gB3 = wot + (size_t)col * Dn + rk * 8;
  }
  const __bf16* gA;
  {
    int c   = tid;
    int row = c >> 2;
    int rk  = (c & 3) ^ ((row >> 1) & 3);
    gA = aout + (size_t)(m0 + row) * Dn + rk * 8;
  }

  int fAo0, fAo1, fAo2, fAo3, fBo[8];
  {
    int row;
    row = rowg * 64 + 0 * 16 + l15; fAo0 = row * BKn + (quad ^ ((row >> 1) & 3)) * 8;
    row = rowg * 64 + 1 * 16 + l15; fAo1 = row * BKn + (quad ^ ((row >> 1) & 3)) * 8;
    row = rowg * 64 + 2 * 16 + l15; fAo2 = row * BKn + (quad ^ ((row >> 1) & 3)) * 8;
    row = rowg * 64 + 3 * 16 + l15; fAo3 = row * BKn + (quad ^ ((row >> 1) & 3)) * 8;
#pragma unroll
    for (int tc = 0; tc < 8; ++tc) {
      int col = colg * 128 + tc * 16 + l15;
      fBo[tc] = 4096 + col * BKn + (quad ^ ((col >> 1) & 3)) * 8;
    }
  }

  const int dA = wave * 512;
  const int dB = 4096 + wave * 2048;

  floatx4 acc[4][8];
  const floatx4 zero = {0.f, 0.f, 0.f, 0.f};
#pragma unroll
  for (int i = 0; i < 4; ++i)
#pragma unroll
    for (int j = 0; j < 8; ++j) acc[i][j] = zero;

  PIPE_STAGE_A(0); PIPE_STAGE_B(0);
  PIPE_STAGE_A(1); PIPE_STAGE_B(1);
  asm volatile("s_waitcnt vmcnt(5)\n\ts_barrier" ::: "memory");

  // 16 K-steps; stage t+2 at steps 0..13
#pragma unroll 1
  for (int it = 0; it < 4; ++it) {           // steps 0..11
    PIPE_STEP(0, 2, true, "5");
    PIPE_STEP(1, 0, true, "5");
    PIPE_STEP(2, 1, true, "5");
  }
  PIPE_STEP(0, 2, true, "5");                // step 12 (stages step 14)
  PIPE_STEP(1, 0, true, "5");                // step 13 (stages step 15)
  PIPE_STEP(2, 0, false, "0");               // step 14
  PIPE_STEP(0, 0, false, "0");               // step 15

#pragma unroll
  for (int m = 0; m < 4; ++m)
#pragma unroll
    for (int r = 0; r < 4; ++r) {
      int row = rowg * 64 + m * 16 + quad * 4 + r;
#pragma unroll
      for (int n = 0; n < 8; ++n) {
        int col = colg * 128 + n * 16 + l15;
        out[(size_t)(m0 + row) * Dn + col] = acc[m][n][r] + bo[col];
      }
    }
}

// ============================ workspace layout ==============================
static const size_t OFF_XPAD = 0;                     // 46,137,344 B (bf16 Xpad)
static const size_t OFF_WCT  = 46137344;              //  4,718,592 B
static const size_t OFF_WOT  = 50855936;              //    524,288 B
static const size_t OFF_WQFT = 51380224;              //     65,536 B
static const size_t OFF_QKV  = 51445760;              // 125,829,120 B
static const size_t OFF_QFP  = 177274880;             //  1,310,720 B
static const size_t OFF_BIAS = 178585600;             //     12,800 B
static const size_t OFF_AOUT = 0;                     // overlays Xpad (dead after k_qfqp/k_qkv)

extern "C" void kernel_launch(void* const* d_in, const int* in_sizes, int n_in,
                              void* d_out, int out_size, void* d_ws, size_t ws_size,
                              hipStream_t stream) {
  (void)in_sizes; (void)n_in; (void)out_size; (void)ws_size;
  const float* x     = (const float*)d_in[0];
  const float* Wq    = (const float*)d_in[1];
  const float* Wk    = (const float*)d_in[2];
  const float* Wv    = (const float*)d_in[3];
  const float* gq_g  = (const float*)d_in[4];
  const float* gq_b  = (const float*)d_in[5];
  const float* gk_g  = (const float*)d_in[6];
  const float* gk_b  = (const float*)d_in[7];
  const float* gv_g  = (const float*)d_in[8];
  const float* gv_b  = (const float*)d_in[9];
  const float* rel   = (const float*)d_in[10];
  const float* gsb   = (const float*)d_in[11];
  const float* alpha = (const float*)d_in[12];
  const float* Wqf   = (const float*)d_in[13];
  const float* bqf   = (const float*)d_in[14];
  const float* Wqp   = (const float*)d_in[15];
  const float* bqp   = (const float*)d_in[16];
  const float* Wo    = (const float*)d_in[17];
  const float* bo    = (const float*)d_in[18];
  float* out = (float*)d_out;
  char* ws = (char*)d_ws;

  __bf16* xpad = (__bf16*)(ws + OFF_XPAD);
  __bf16* wct  = (__bf16*)(ws + OFF_WCT);
  __bf16* wot  = (__bf16*)(ws + OFF_WOT);
  __bf16* wqft = (__bf16*)(ws + OFF_WQFT);
  __bf16* qkv  = (__bf16*)(ws + OFF_QKV);
  float*  qfp  = (float*)(ws + OFF_QFP);
  float*  bias = (float*)(ws + OFF_BIAS);
  __bf16* aout = (__bf16*)(ws + OFF_AOUT);

  k_prep_xpad<<<(Bn * NPn * (Dn / 8) + 255) / 256, 256, 0, stream>>>(x, xpad);
  k_prep_wct <<<(K3n * K3n + 255) / 256, 256, 0, stream>>>(Wq, Wk, Wv, wct);
  k_prep_wot <<<(Dn * Dn + 255) / 256, 256, 0, stream>>>(Wo, wot);
  k_prep_wqft<<<(Dn * 64 + 255) / 256, 256, 0, stream>>>(Wqf, wqft);
  k_bias     <<<(Hn * Nn * Nn + 255) / 256, 256, 0, stream>>>(rel, gsb, alpha, bqp, bias);

  k_qkv <<<Mn / 128 * 3, 512, 0, stream>>>(xpad, wct, gq_g, gq_b, gk_g, gk_b, gv_g, gv_b, qkv);
  k_qfqp<<<Mn / 64, 256, 0, stream>>>(xpad, wqft, bqf, Wqp, qfp);
  k_attn<<<(Bn * Hn) / 4, 256, 0, stream>>>(qkv, qfp, bias, aout);
  k_oproj<<<Mn / 128, 512, 0, stream>>>(aout, wot, bo, out);
}

// Round 4
// 569.701 us; speedup vs baseline: 1.0600x; 1.0600x over previous
//
#include <hip/hip_runtime.h>
#include <stdint.h>

#define Bn   2048
#define Nn   20
#define Dn   512
#define Hn   8
#define Mn   (Bn*Nn)      // 40960 rows
#define K3n  1536
#define NPn  22           // padded sequence rows
#define BKn  32

typedef __attribute__((ext_vector_type(4))) float  floatx4;
typedef __attribute__((ext_vector_type(8))) __bf16 bf16x8;
typedef __attribute__((ext_vector_type(4))) __bf16 bf16x4;

// -------- async global->LDS, 16B per lane; LDS base must be wave-uniform ----
__device__ __forceinline__ void gload_lds16(const void* g, void* l) {
  __builtin_amdgcn_global_load_lds(
      (const __attribute__((address_space(1))) void*)g,
      (__attribute__((address_space(3))) void*)l, 16, 0, 0);
}

// ============================ prep kernels ==================================
// Xpad[b][0]=0, Xpad[b][n]=bf16(x[b][n-1]), Xpad[b][21]=0
__global__ void k_prep_xpad(const float* __restrict__ x, __bf16* __restrict__ xpad) {
  int idx = blockIdx.x * 256 + threadIdx.x;      // over B*22*64 chunks of 8
  int d8 = idx & 63;
  int t  = idx >> 6;                              // b*22 + n
  if (t >= Bn * NPn) return;
  int n = t % NPn;
  int b = t / NPn;
  bf16x8 v;
  if (n == 0 || n == NPn - 1) {
#pragma unroll
    for (int e = 0; e < 8; ++e) v[e] = (__bf16)0.f;
  } else {
    const float4 x0 = *(const float4*)(x + (size_t)((b * Nn + n - 1) * Dn) + d8 * 8);
    const float4 x1 = *(const float4*)(x + (size_t)((b * Nn + n - 1) * Dn) + d8 * 8 + 4);
    v[0] = (__bf16)x0.x; v[1] = (__bf16)x0.y; v[2] = (__bf16)x0.z; v[3] = (__bf16)x0.w;
    v[4] = (__bf16)x1.x; v[5] = (__bf16)x1.y; v[6] = (__bf16)x1.z; v[7] = (__bf16)x1.w;
  }
  *(bf16x8*)(xpad + (size_t)t * Dn + d8 * 8) = v;
}

// wctf: MFMA-fragment-ordered conv weights.
// Element (((kt*96 + cb)*64 + l)*8 + e) = B^T[col][k] where
//   col = cb*16 + (l&15), k = kt*32 + (l>>4)*8 + e,
//   B^T[j][kk] = Wseg[o][i][kker], j = seg*512+o, kk = kker*512+i.
// A wave's fragment load (tc) is then 64 lanes x 16B fully contiguous (1KB).
__global__ void k_prep_wctf(const float* __restrict__ Wq, const float* __restrict__ Wk,
                            const float* __restrict__ Wv, __bf16* __restrict__ wctf) {
  int t = blockIdx.x * 256 + threadIdx.x;        // 0 .. 48*96*64-1
  if (t >= 48 * 96 * 64) return;
  int l  = t & 63;
  int cb = (t >> 6) % 96;
  int kt = t / (96 * 64);
  int col = cb * 16 + (l & 15);
  int k   = kt * 32 + (l >> 4) * 8;
  int seg = col >> 9, o = col & 511;
  int kker = k >> 9, i = k & 511;
  const float* W = (seg == 0) ? Wq : ((seg == 1) ? Wk : Wv);
  const float* s = W + ((size_t)o * 512 + i) * 3 + kker;
  bf16x8 v;
#pragma unroll
  for (int e = 0; e < 8; ++e) v[e] = (__bf16)s[e * 3];
  *(bf16x8*)(wctf + (size_t)t * 8) = v;
}

// wotf: fragment-ordered Wo^T. Element (((kt*32+cb)*64+l)*8+e) = Wo[k][col],
// col = cb*16+(l&15), k = kt*32+(l>>4)*8+e.
__global__ void k_prep_wotf(const float* __restrict__ Wo, __bf16* __restrict__ wotf) {
  int t = blockIdx.x * 256 + threadIdx.x;        // 0 .. 16*32*64-1
  if (t >= 16 * 32 * 64) return;
  int l  = t & 63;
  int cb = (t >> 6) & 31;
  int kt = t / (32 * 64);
  int col = cb * 16 + (l & 15);
  int k   = kt * 32 + (l >> 4) * 8;
  const float* s = Wo + (size_t)k * 512 + col;
  bf16x8 v;
#pragma unroll
  for (int e = 0; e < 8; ++e) v[e] = (__bf16)s[(size_t)e * 512];
  *(bf16x8*)(wotf + (size_t)t * 8) = v;
}

// WqfT[dq][d] = Wqf[d][dq]
__global__ void k_prep_wqft(const float* __restrict__ Wqf, __bf16* __restrict__ wqft) {
  int idx = blockIdx.x * 256 + threadIdx.x;
  if (idx >= Dn * 64) return;
  int d = idx & 511, dq = idx >> 9;
  wqft[idx] = (__bf16)Wqf[d * 64 + dq];
}

// bias[h][i][j] = rel_table[i-j+19][h] + alpha*gsb[h][i][j] + bqp[h]
__global__ void k_bias(const float* __restrict__ rel, const float* __restrict__ gsb,
                       const float* __restrict__ alpha, const float* __restrict__ bqp,
                       float* __restrict__ bias) {
  int idx = blockIdx.x * 256 + threadIdx.x;
  if (idx >= Hn * Nn * Nn) return;
  int j = idx % Nn;
  int i = (idx / Nn) % Nn;
  int h = idx / (Nn * Nn);
  bias[idx] = rel[(i - j + Nn - 1) * Hn + h] + alpha[0] * gsb[idx] + bqp[h];
}

// ===== barrier-free wave-private GEMM step machinery ========================
// Each wave owns a 64x128 output slice. B fragments stream coalesced from the
// fragment-ordered weight buffer (L2-hot) into registers, double-buffered
// (bA/bB) one step ahead. A is staged into the wave's PRIVATE 2x4KB LDS slice
// via gload_lds (no cross-wave readers -> no barriers; the wave's own
// vmcnt(0) at step end covers both its A-stage and its B-prefetch).
// Requires in scope: gW, gA0..gA3, myA, fAo[4], acc[4][8], bA, bB.
#define LOADB(DST, ADV) do {                                           \
    _Pragma("unroll")                                                  \
    for (int _tc = 0; _tc < 8; ++_tc)                                  \
      DST[_tc] = *(const bf16x8*)(gW + _tc * 512);                     \
    gW += (ADV);                                                       \
  } while (0)

#define STAGEA(NB) do {                                                \
    gload_lds16(gA0, myA + (NB) * 2048 +    0); gA0 += BKn;            \
    gload_lds16(gA1, myA + (NB) * 2048 +  512); gA1 += BKn;            \
    gload_lds16(gA2, myA + (NB) * 2048 + 1024); gA2 += BKn;            \
    gload_lds16(gA3, myA + (NB) * 2048 + 1536); gA3 += BKn;            \
  } while (0)

#define GSTEP(KT, CUR, NXT, CB, NB, LASTKT, ADV) do {                  \
    const __bf16* _L = myA + (CB) * 2048;                              \
    bf16x8 _a0 = *(const bf16x8*)(_L + fAo[0]);                        \
    bf16x8 _a1 = *(const bf16x8*)(_L + fAo[1]);                        \
    bf16x8 _a2 = *(const bf16x8*)(_L + fAo[2]);                        \
    bf16x8 _a3 = *(const bf16x8*)(_L + fAo[3]);                        \
    if ((KT) < (LASTKT)) { LOADB(NXT, ADV); STAGEA(NB); }              \
    __builtin_amdgcn_s_setprio(1);                                     \
    _Pragma("unroll")                                                  \
    for (int _tc = 0; _tc < 8; ++_tc) {                                \
      acc[0][_tc] = __builtin_amdgcn_mfma_f32_16x16x32_bf16(_a0, CUR[_tc], acc[0][_tc], 0, 0, 0); \
      acc[1][_tc] = __builtin_amdgcn_mfma_f32_16x16x32_bf16(_a1, CUR[_tc], acc[1][_tc], 0, 0, 0); \
      acc[2][_tc] = __builtin_amdgcn_mfma_f32_16x16x32_bf16(_a2, CUR[_tc], acc[2][_tc], 0, 0, 0); \
      acc[3][_tc] = __builtin_amdgcn_mfma_f32_16x16x32_bf16(_a3, CUR[_tc], acc[3][_tc], 0, 0, 0); \
    }                                                                  \
    __builtin_amdgcn_s_setprio(0);                                     \
    asm volatile("s_waitcnt vmcnt(0)" ::: "memory");                   \
  } while (0)

// ================= QKV conv-GEMM + LayerNorm + residual =====================
// 64x512 tile, 256 thr = 4 waves (wv = col group), wave tile 64x128 = 4x8
// frags of 16x16x32 bf16. K = 1536 (conv window via 3 adjacent xpad rows).
// LDS 32KB + VGPR<=256 => 2 independent blocks/CU; no intra-loop barriers.
// Grid 1920 = 8 XCDs x {seg-major: 3 segs x 80 m-tiles}: each XCD's 1.57MB
// B panel stays L2-hot for 80 consecutive blocks.
__global__ __launch_bounds__(256, 2)
void k_qkv(const __bf16* __restrict__ xpad, const __bf16* __restrict__ wctf,
           const float* __restrict__ gq_g, const float* __restrict__ gq_b,
           const float* __restrict__ gk_g, const float* __restrict__ gk_b,
           const float* __restrict__ gv_g, const float* __restrict__ gv_b,
           __bf16* __restrict__ qkv) {
  __shared__ __bf16 lA[4][2][2048];    // per-wave private 2x4KB A buffers
  __shared__ float red1[256];          // 64 rows x 4 col-groups
  __shared__ float red2[256];

  const int tid  = threadIdx.x;
  const int wv   = tid >> 6;           // wave / col group 0..3
  const int lane = tid & 63;
  const int quad = lane >> 4;
  const int l15  = lane & 15;

  // seg-major XCD swizzle
  const int bid   = blockIdx.x;
  const int xcd   = bid & 7;
  const int local = bid >> 3;          // 0..239
  const int seg   = local / 80;        // 0..2
  const int mt    = xcd * 80 + (local % 80);
  const int m0    = mt * 64;

  // --- A staging sources: wave loads its own full 64x32 tile (4 rounds) ---
  const __bf16 *gA0, *gA1, *gA2, *gA3;
  {
    int c, row, rk, grow, b, n;
    c = 0 * 64 + lane; row = c >> 2; rk = (c & 3) ^ ((row >> 1) & 3);
    grow = m0 + row; b = grow / Nn; n = grow - b * Nn;
    gA0 = xpad + (size_t)(b * NPn + n) * Dn + rk * 8;
    c = 1 * 64 + lane; row = c >> 2; rk = (c & 3) ^ ((row >> 1) & 3);
    grow = m0 + row; b = grow / Nn; n = grow - b * Nn;
    gA1 = xpad + (size_t)(b * NPn + n) * Dn + rk * 8;
    c = 2 * 64 + lane; row = c >> 2; rk = (c & 3) ^ ((row >> 1) & 3);
    grow = m0 + row; b = grow / Nn; n = grow - b * Nn;
    gA2 = xpad + (size_t)(b * NPn + n) * Dn + rk * 8;
    c = 3 * 64 + lane; row = c >> 2; rk = (c & 3) ^ ((row >> 1) & 3);
    grow = m0 + row; b = grow / Nn; n = grow - b * Nn;
    gA3 = xpad + (size_t)(b * NPn + n) * Dn + rk * 8;
  }

  // --- B fragment stream base: wave reads cb = seg*32 + wv*8 + tc ---
  const __bf16* gW = wctf + ((size_t)(seg * 32 + wv * 8) * 512) + lane * 8;

  // --- A fragment LDS offsets (within this wave's buffer) ---
  int fAo[4];
#pragma unroll
  for (int mi = 0; mi < 4; ++mi) {
    int row = mi * 16 + l15;
    fAo[mi] = row * BKn + (quad ^ ((row >> 1) & 3)) * 8;
  }
  __bf16* myA = &lA[wv][0][0];

  floatx4 acc[4][8];
  const floatx4 zero = {0.f, 0.f, 0.f, 0.f};
#pragma unroll
  for (int i = 0; i < 4; ++i)
#pragma unroll
    for (int j = 0; j < 8; ++j) acc[i][j] = zero;

  bf16x8 bA[8], bB[8];

  // prologue: stage A(0), load B(0)
  STAGEA(0);
  LOADB(bA, 49152);
  asm volatile("s_waitcnt vmcnt(0)" ::: "memory");

#pragma unroll 1
  for (int it = 0; it < 24; ++it) {            // 48 K-steps, 2 per iter
    GSTEP(2 * it,     bA, bB, 0, 1, 47, 49152);
    GSTEP(2 * it + 1, bB, bA, 1, 0, 47, 49152);
  }

  // --- fused LayerNorm + residual epilogue ---
  float s1[16], s2[16];
#pragma unroll
  for (int mi = 0; mi < 4; ++mi)
#pragma unroll
    for (int r = 0; r < 4; ++r) {
      float a = 0.f, b2 = 0.f;
#pragma unroll
      for (int tc = 0; tc < 8; ++tc) { float v = acc[mi][tc][r]; a += v; b2 += v * v; }
      s1[mi * 4 + r] = a; s2[mi * 4 + r] = b2;
    }
#pragma unroll
  for (int off = 1; off < 16; off <<= 1)
#pragma unroll
    for (int i = 0; i < 16; ++i) {
      s1[i] += __shfl_xor(s1[i], off, 64);
      s2[i] += __shfl_xor(s2[i], off, 64);
    }
  if (l15 == 0) {
#pragma unroll
    for (int i = 0; i < 16; ++i) {
      int mi = i >> 2, r = i & 3;
      int row = mi * 16 + quad * 4 + r;
      red1[row * 4 + wv] = s1[i];
      red2[row * 4 + wv] = s2[i];
    }
  }
  __syncthreads();

  const float* gg = (seg == 0) ? gq_g : ((seg == 1) ? gk_g : gv_g);
  const float* bb = (seg == 0) ? gq_b : ((seg == 1) ? gk_b : gv_b);
#pragma unroll
  for (int mi = 0; mi < 4; ++mi)
#pragma unroll
    for (int r = 0; r < 4; ++r) {
      int row = mi * 16 + quad * 4 + r;
      float su = red1[row * 4] + red1[row * 4 + 1] + red1[row * 4 + 2] + red1[row * 4 + 3];
      float sq = red2[row * 4] + red2[row * 4 + 1] + red2[row * 4 + 2] + red2[row * 4 + 3];
      float mn = su * (1.f / 512.f);
      float vv = sq * (1.f / 512.f) - mn * mn;
      float rstd = rsqrtf(vv + 1e-5f);
      int grow = m0 + row;
      int b = grow / Nn, n2 = grow - b * Nn;
      const __bf16* xr = xpad + (size_t)(b * NPn + n2 + 1) * Dn;  // bf16 residual (L2-hot)
#pragma unroll
      for (int tc = 0; tc < 8; ++tc) {
        int col = wv * 128 + tc * 16 + l15;
        float val = (acc[mi][tc][r] - mn) * rstd * gg[col] + bb[col] + (float)xr[col];
        qkv[(size_t)grow * K3n + seg * 512 + col] = (__bf16)val;
      }
    }
}

// ======== qfp = tanh(x @ Wqf + bqf) @ Wqp  (fused, fp32 out) ================
// Block: 64 rows x 64 cols, 256 thr = 4 waves, wave = 16 rows x 64 cols. K=512.
// Epilogue: per-row dot with Wqp via shfl reduction over l15 -> qfp[row][8].
__global__ __launch_bounds__(256)
void k_qfqp(const __bf16* __restrict__ xpad, const __bf16* __restrict__ wqft,
            const float* __restrict__ bqf, const float* __restrict__ wqp,
            float* __restrict__ qfp) {
  __shared__ __bf16 sA[64 * BKn];
  __shared__ __bf16 sB[64 * BKn];
  __shared__ float lWqpT[8 * 64];   // [h][col]
  const int tid  = threadIdx.x;
  const int wave = tid >> 6;
  const int lane = tid & 63;
  const int quad = lane >> 4;
  const int l15  = lane & 15;
  const int m0   = blockIdx.x * 64;

#pragma unroll
  for (int t = tid; t < 512; t += 256) {
    int col = t & 63, h = t >> 6;
    lWqpT[t] = wqp[col * 8 + h];
  }

  int c = wave * 64 + lane;
  int rowc = c >> 2;
  int rk   = (c & 3) ^ ((rowc >> 1) & 3);
  int grow = m0 + rowc;
  int b = grow / Nn, n = grow - b * Nn;
  const __bf16* gA = xpad + (size_t)(b * NPn + n + 1) * Dn + rk * 8;  // x[b][n]
  const __bf16* gB = wqft + (size_t)rowc * Dn + rk * 8;

  int frow = wave * 16 + l15;
  const __bf16* fA = sA + frow * BKn + (quad ^ ((frow >> 1) & 3)) * 8;
  const __bf16* fB[4];
#pragma unroll
  for (int tc = 0; tc < 4; ++tc) {
    int col = tc * 16 + l15;
    fB[tc] = sB + col * BKn + (quad ^ ((col >> 1) & 3)) * 8;
  }

  const floatx4 zero = {0.f, 0.f, 0.f, 0.f};
  floatx4 acc[4] = {zero, zero, zero, zero};

  for (int kt = 0; kt < Dn / BKn; ++kt) {
    gload_lds16(gA, sA + wave * 512);
    gload_lds16(gB, sB + wave * 512);
    __syncthreads();
    bf16x8 a = *(const bf16x8*)fA;
#pragma unroll
    for (int tc = 0; tc < 4; ++tc)
      acc[tc] = __builtin_amdgcn_mfma_f32_16x16x32_bf16(a, *(const bf16x8*)fB[tc], acc[tc], 0, 0, 0);
    __syncthreads();
    gA += BKn; gB += BKn;
  }

  // epilogue: t = tanh(acc + bqf); qfp[row][h] = sum_col t*WqpT[h][col]
  float part[4][8];
#pragma unroll
  for (int r = 0; r < 4; ++r)
#pragma unroll
    for (int h = 0; h < 8; ++h) part[r][h] = 0.f;
#pragma unroll
  for (int tc = 0; tc < 4; ++tc) {
    int col = tc * 16 + l15;
    float bq = bqf[col];
#pragma unroll
    for (int r = 0; r < 4; ++r) {
      float t = tanhf(acc[tc][r] + bq);
#pragma unroll
      for (int h = 0; h < 8; ++h) part[r][h] += t * lWqpT[h * 64 + col];
    }
  }
#pragma unroll
  for (int off = 1; off < 16; off <<= 1)
#pragma unroll
    for (int r = 0; r < 4; ++r)
#pragma unroll
      for (int h = 0; h < 8; ++h) part[r][h] += __shfl_xor(part[r][h], off, 64);
  if (l15 == 0) {
#pragma unroll
    for (int r = 0; r < 4; ++r) {
      int row = wave * 16 + quad * 4 + r;
#pragma unroll
      for (int h = 0; h < 8; ++h)
        qfp[(size_t)(m0 + row) * 8 + h] = part[r][h];
    }
  }
}

// =========================== attention (fp32) ===============================
// One wave per (b,h). scores = qk^T/8 + bias[h] + qfp_i - qfp_j; softmax; @v.
__global__ __launch_bounds__(256)
void k_attn(const __bf16* __restrict__ qkv, const float* __restrict__ qfp,
            const float* __restrict__ bias, __bf16* __restrict__ aout) {
  __shared__ float sq[4][Nn * 64];
  __shared__ float sk[4][Nn * 68];
  __shared__ float sv[4][Nn * 68];
  __shared__ float sp[4][Nn * Nn];
  __shared__ float sf[4][Nn];
  const int tid  = threadIdx.x;
  const int w    = tid >> 6;
  const int lane = tid & 63;
  const int p0 = blockIdx.x * 4 + w;
  const int b = p0 >> 3, h = p0 & 7;
  const __bf16* qb = qkv + (size_t)b * Nn * K3n + h * 64;

  // vectorized staging: 160 bf16x8 chunks per matrix
  for (int idx = lane; idx < 160; idx += 64) {
    int n = idx >> 3, c = (idx & 7) * 8;
    bf16x8 qv = *(const bf16x8*)(qb + (size_t)n * K3n + c);
    bf16x8 kv = *(const bf16x8*)(qb + (size_t)n * K3n + 512 + c);
    bf16x8 vv = *(const bf16x8*)(qb + (size_t)n * K3n + 1024 + c);
#pragma unroll
    for (int e = 0; e < 8; ++e) {
      sq[w][n * 64 + c + e] = (float)qv[e];
      sk[w][n * 68 + c + e] = (float)kv[e];
      sv[w][n * 68 + c + e] = (float)vv[e];
    }
  }
  if (lane < Nn) sf[w][lane] = qfp[(size_t)(b * Nn + lane) * 8 + h];
  __syncthreads();

  // scores: all 64 lanes over 400 (i,j) pairs
  const float* bh = bias + h * Nn * Nn;
  for (int p = lane; p < Nn * Nn; p += 64) {
    int i = p / Nn, j = p - i * Nn;
    const float4* q4 = (const float4*)&sq[w][i * 64];
    const float4* k4 = (const float4*)&sk[w][j * 68];
    float s = 0.f;
#pragma unroll
    for (int d4 = 0; d4 < 16; ++d4) {
      float4 qa = q4[d4], ka = k4[d4];
      s += qa.x * ka.x + qa.y * ka.y + qa.z * ka.z + qa.w * ka.w;
    }
    sp[w][p] = s * 0.125f + bh[p] + sf[w][i] - sf[w][j];
  }
  __syncthreads();
  if (lane < Nn) {
    int i = lane;
    float* row = &sp[w][i * Nn];
    float mx = row[0];
    for (int j = 1; j < Nn; ++j) mx = fmaxf(mx, row[j]);
    float sum = 0.f;
    for (int j = 0; j < Nn; ++j) { float e = __expf(row[j] - mx); row[j] = e; sum += e; }
    float inv = 1.f / sum;
    for (int j = 0; j < Nn; ++j) row[j] *= inv;
  }
  __syncthreads();
  for (int i = 0; i < Nn; ++i) {
    float a = 0.f;
#pragma unroll
    for (int j = 0; j < Nn; ++j) a += sp[w][i * Nn + j] * sv[w][j * 68 + lane];
    aout[(size_t)(b * Nn + i) * Dn + h * 64 + lane] = (__bf16)a;
  }
}

// ==================== out = attn_out @ Wo + bo (fp32 out) ===================
// Barrier-free wave-private structure, K=512 -> 16 steps. Grid 640 = 8x80.
__global__ __launch_bounds__(256, 2)
void k_oproj(const __bf16* __restrict__ aout, const __bf16* __restrict__ wotf,
             const float* __restrict__ bo, float* __restrict__ out) {
  __shared__ __bf16 lA[4][2][2048];    // per-wave private 2x4KB
  const int tid  = threadIdx.x;
  const int wv   = tid >> 6;
  const int lane = tid & 63;
  const int quad = lane >> 4;
  const int l15  = lane & 15;

  const int bid = blockIdx.x;
  const int m0  = ((bid & 7) * 80 + (bid >> 3)) * 64;

  const __bf16 *gA0, *gA1, *gA2, *gA3;
  {
    int c, row, rk;
    c = 0 * 64 + lane; row = c >> 2; rk = (c & 3) ^ ((row >> 1) & 3);
    gA0 = aout + (size_t)(m0 + row) * Dn + rk * 8;
    c = 1 * 64 + lane; row = c >> 2; rk = (c & 3) ^ ((row >> 1) & 3);
    gA1 = aout + (size_t)(m0 + row) * Dn + rk * 8;
    c = 2 * 64 + lane; row = c >> 2; rk = (c & 3) ^ ((row >> 1) & 3);
    gA2 = aout + (size_t)(m0 + row) * Dn + rk * 8;
    c = 3 * 64 + lane; row = c >> 2; rk = (c & 3) ^ ((row >> 1) & 3);
    gA3 = aout + (size_t)(m0 + row) * Dn + rk * 8;
  }
  const __bf16* gW = wotf + ((size_t)(wv * 8) * 512) + lane * 8;

  int fAo[4];
#pragma unroll
  for (int mi = 0; mi < 4; ++mi) {
    int row = mi * 16 + l15;
    fAo[mi] = row * BKn + (quad ^ ((row >> 1) & 3)) * 8;
  }
  __bf16* myA = &lA[wv][0][0];

  floatx4 acc[4][8];
  const floatx4 zero = {0.f, 0.f, 0.f, 0.f};
#pragma unroll
  for (int i = 0; i < 4; ++i)
#pragma unroll
    for (int j = 0; j < 8; ++j) acc[i][j] = zero;

  bf16x8 bA[8], bB[8];

  STAGEA(0);
  LOADB(bA, 16384);
  asm volatile("s_waitcnt vmcnt(0)" ::: "memory");

#pragma unroll 1
  for (int it = 0; it < 8; ++it) {             // 16 K-steps
    GSTEP(2 * it,     bA, bB, 0, 1, 15, 16384);
    GSTEP(2 * it + 1, bB, bA, 1, 0, 15, 16384);
  }

#pragma unroll
  for (int mi = 0; mi < 4; ++mi)
#pragma unroll
    for (int r = 0; r < 4; ++r) {
      int row = mi * 16 + quad * 4 + r;
#pragma unroll
      for (int tc = 0; tc < 8; ++tc) {
        int col = wv * 128 + tc * 16 + l15;
        out[(size_t)(m0 + row) * Dn + col] = acc[mi][tc][r] + bo[col];
      }
    }
}

// ============================ workspace layout ==============================
static const size_t OFF_XPAD = 0;                     // 46,137,344 B (bf16 Xpad)
static const size_t OFF_WCT  = 46137344;              //  4,718,592 B (wctf)
static const size_t OFF_WOT  = 50855936;              //    524,288 B (wotf)
static const size_t OFF_WQFT = 51380224;              //     65,536 B
static const size_t OFF_QKV  = 51445760;              // 125,829,120 B
static const size_t OFF_QFP  = 177274880;             //  1,310,720 B
static const size_t OFF_BIAS = 178585600;             //     12,800 B
static const size_t OFF_AOUT = 0;                     // overlays Xpad (dead after k_qfqp/k_qkv)

extern "C" void kernel_launch(void* const* d_in, const int* in_sizes, int n_in,
                              void* d_out, int out_size, void* d_ws, size_t ws_size,
                              hipStream_t stream) {
  (void)in_sizes; (void)n_in; (void)out_size; (void)ws_size;
  const float* x     = (const float*)d_in[0];
  const float* Wq    = (const float*)d_in[1];
  const float* Wk    = (const float*)d_in[2];
  const float* Wv    = (const float*)d_in[3];
  const float* gq_g  = (const float*)d_in[4];
  const float* gq_b  = (const float*)d_in[5];
  const float* gk_g  = (const float*)d_in[6];
  const float* gk_b  = (const float*)d_in[7];
  const float* gv_g  = (const float*)d_in[8];
  const float* gv_b  = (const float*)d_in[9];
  const float* rel   = (const float*)d_in[10];
  const float* gsb   = (const float*)d_in[11];
  const float* alpha = (const float*)d_in[12];
  const float* Wqf   = (const float*)d_in[13];
  const float* bqf   = (const float*)d_in[14];
  const float* Wqp   = (const float*)d_in[15];
  const float* bqp   = (const float*)d_in[16];
  const float* Wo    = (const float*)d_in[17];
  const float* bo    = (const float*)d_in[18];
  float* out = (float*)d_out;
  char* ws = (char*)d_ws;

  __bf16* xpad = (__bf16*)(ws + OFF_XPAD);
  __bf16* wctf = (__bf16*)(ws + OFF_WCT);
  __bf16* wotf = (__bf16*)(ws + OFF_WOT);
  __bf16* wqft = (__bf16*)(ws + OFF_WQFT);
  __bf16* qkv  = (__bf16*)(ws + OFF_QKV);
  float*  qfp  = (float*)(ws + OFF_QFP);
  float*  bias = (float*)(ws + OFF_BIAS);
  __bf16* aout = (__bf16*)(ws + OFF_AOUT);

  k_prep_xpad<<<(Bn * NPn * (Dn / 8) + 255) / 256, 256, 0, stream>>>(x, xpad);
  k_prep_wctf<<<(48 * 96 * 64 + 255) / 256, 256, 0, stream>>>(Wq, Wk, Wv, wctf);
  k_prep_wotf<<<(16 * 32 * 64 + 255) / 256, 256, 0, stream>>>(Wo, wotf);
  k_prep_wqft<<<(Dn * 64 + 255) / 256, 256, 0, stream>>>(Wqf, wqft);
  k_bias     <<<(Hn * Nn * Nn + 255) / 256, 256, 0, stream>>>(rel, gsb, alpha, bqp, bias);

  k_qkv <<<Mn / 64 * 3, 256, 0, stream>>>(xpad, wctf, gq_g, gq_b, gk_g, gk_b, gv_g, gv_b, qkv);
  k_qfqp<<<Mn / 64, 256, 0, stream>>>(xpad, wqft, bqf, Wqp, qfp);
  k_attn<<<(Bn * Hn) / 4, 256, 0, stream>>>(qkv, qfp, bias, aout);
  k_oproj<<<Mn / 64, 256, 0, stream>>>(aout, wotf, bo, out);
}